// Round 6
// baseline (854.180 us; speedup 1.0000x reference)
//
#include <hip/hip_runtime.h>

#define BB_ 4
#define TT_ 8
#define CC_ 64
#define HW 4096
#define UMAP 1024      // floats per (b,c) spectrum map: 32 ky * 16 kx * 2
#define STEP 0.09817477042468103f   // 2*pi/64

// ws float offsets (SPART slot retained in layout but no longer used)
#define OFF_UXALL 0                                     // 8*256*1024
#define OFF_UH    (OFF_UXALL + TT_*256*UMAP)            // 256*1024
#define OFF_URH   (OFF_UH + 256*UMAP)                   // 256*1024
#define OFF_SX    (OFF_URH + 256*UMAP)                  // 3 slots * 8 t * 256 maps * 1024
#define OFF_SPART (OFF_SX + 3*TT_*256*UMAP)
#define OFF_H     (OFF_SPART + 2*8*256*UMAP)
#define OFF_Z     (OFF_H + BB_*CC_*HW)
#define OFF_RH    (OFF_Z + BB_*CC_*HW)
#define OFF_PH    (OFF_RH + BB_*CC_*HW)

// ---------------- init: h = bias, Uh = spectrum of constant map ----------------
__global__ __launch_bounds__(256) void k_init(float* __restrict__ hb,
                                              float* __restrict__ Uh,
                                              const float* __restrict__ bias_h) {
    float v = bias_h[0];
    int blk = blockIdx.x;
    if (blk < 1024) {
        int idx = (blk * 256 + threadIdx.x) * 4;
        *(float4*)(hb + idx) = make_float4(v, v, v, v);
    } else {
        // spectrum of constant v map: only (ky=0,kx=0) = 4096*v/64 = 64*v
        int map = blk - 1024;
        float4 z = make_float4(0.f, 0.f, 0.f, 0.f);
        if (threadIdx.x == 0) z.x = 64.f * v;
        *(float4*)(Uh + (size_t)map * UMAP + threadIdx.x * 4) = z;
    }
}

// ---------------- forward partial DFT stages, 256-thread variant ----------------
__device__ __forceinline__ void dft_stages(const float* __restrict__ su,
                                           float* __restrict__ FxR, float* __restrict__ FxI,
                                           float* __restrict__ dst) {
    int tid = threadIdx.x;
    int kx = tid & 15, yb = tid >> 4;
    float stc, sts;
    __sincosf(-STEP * (float)kx, &sts, &stc);
    float wr = 1.f, wi = 0.f;
    float aR[4] = {0, 0, 0, 0}, aI[4] = {0, 0, 0, 0};
    for (int x = 0; x < 64; x++) {
        #pragma unroll
        for (int j = 0; j < 4; j++) {
            float v = su[(yb + 16 * j) * 65 + x];
            aR[j] = fmaf(v, wr, aR[j]);
            aI[j] = fmaf(v, wi, aI[j]);
        }
        float t = wr * stc - wi * sts;
        wi = wr * sts + wi * stc;
        wr = t;
    }
    #pragma unroll
    for (int j = 0; j < 4; j++) {
        FxR[(yb + 16 * j) * 16 + kx] = aR[j];
        FxI[(yb + 16 * j) * 16 + kx] = aI[j];
    }
    __syncthreads();
    int kb = tid >> 4;
    float c0, s0, c1, s1;
    __sincosf(-STEP * (float)kb, &s0, &c0);
    __sincosf(-STEP * (float)(kb + 48), &s1, &c1);
    float w0r = 1, w0i = 0, w1r = 1, w1i = 0;
    float A0r = 0, A0i = 0, A1r = 0, A1i = 0;
    for (int y = 0; y < 64; y++) {
        float Fr = FxR[y * 16 + kx], Fi = FxI[y * 16 + kx];
        A0r = fmaf(Fr, w0r, A0r); A0r = fmaf(-Fi, w0i, A0r);
        A0i = fmaf(Fr, w0i, A0i); A0i = fmaf(Fi, w0r, A0i);
        A1r = fmaf(Fr, w1r, A1r); A1r = fmaf(-Fi, w1i, A1r);
        A1i = fmaf(Fr, w1i, A1i); A1i = fmaf(Fi, w1r, A1i);
        float t0 = w0r * c0 - w0i * s0; w0i = w0r * s0 + w0i * c0; w0r = t0;
        float t1 = w1r * c1 - w1i * s1; w1i = w1r * s1 + w1i * c1; w1r = t1;
    }
    const float sc = 1.f / 64.f;
    float2* d2 = (float2*)dst;
    d2[kb * 16 + kx]        = make_float2(A0r * sc, A0i * sc);
    d2[(kb + 16) * 16 + kx] = make_float2(A1r * sc, A1i * sc);
}

// ---------------- forward DFT stages, 512-thread variant ------------------------
__device__ __forceinline__ void dft_stages_512(const float* __restrict__ su,
                                               float* __restrict__ FxR, float* __restrict__ FxI,
                                               float* __restrict__ dst) {
    int tid = threadIdx.x;
    int kx = tid & 15, yb = tid >> 4;            // yb 0..31
    float stc, sts;
    __sincosf(-STEP * (float)kx, &sts, &stc);
    float wr = 1.f, wi = 0.f;
    float aR[2] = {0, 0}, aI[2] = {0, 0};
    for (int x = 0; x < 64; x++) {
        #pragma unroll
        for (int j = 0; j < 2; j++) {
            float v = su[(yb + 32 * j) * 65 + x];
            aR[j] = fmaf(v, wr, aR[j]);
            aI[j] = fmaf(v, wi, aI[j]);
        }
        float t = wr * stc - wi * sts;
        wi = wr * sts + wi * stc;
        wr = t;
    }
    #pragma unroll
    for (int j = 0; j < 2; j++) {
        FxR[(yb + 32 * j) * 16 + kx] = aR[j];
        FxI[(yb + 32 * j) * 16 + kx] = aI[j];
    }
    __syncthreads();
    int kb = tid >> 4;                           // 0..31 = output row
    int ky = (kb < 16) ? kb : kb + 32;           // rows 16..31 hold ky 48..63
    float c0, s0;
    __sincosf(-STEP * (float)ky, &s0, &c0);
    float w0r = 1, w0i = 0, A0r = 0, A0i = 0;
    for (int y = 0; y < 64; y++) {
        float Fr = FxR[y * 16 + kx], Fi = FxI[y * 16 + kx];
        A0r = fmaf(Fr, w0r, A0r); A0r = fmaf(-Fi, w0i, A0r);
        A0i = fmaf(Fr, w0i, A0i); A0i = fmaf(Fi, w0r, A0i);
        float t0 = w0r * c0 - w0i * s0; w0i = w0r * s0 + w0i * c0; w0r = t0;
    }
    const float sc = 1.f / 64.f;
    ((float2*)dst)[kb * 16 + kx] = make_float2(A0r * sc, A0i * sc);
}

// ---------------- batched DFT of all x_t maps (once per launch) ----------------
__global__ __launch_bounds__(256) void k_dft_x(const float* __restrict__ x,
                                               float* __restrict__ Uxall) {
    __shared__ float su[64 * 65];
    __shared__ float FxR[1024], FxI[1024];
    int blk = blockIdx.x;
    int t = blk >> 8, map = blk & 255;
    int b = map >> 6, c = map & 63;
    const float* src = x + (((size_t)b * TT_ + t) * CC_ + c) * HW;
    int tid = threadIdx.x;
    #pragma unroll
    for (int k = 0; k < 4; k++) {
        int off = k * 1024 + tid * 4;
        float4 v = *(const float4*)(src + off);
        int y = off >> 6, xx = off & 63;
        su[y * 65 + xx + 0] = v.x; su[y * 65 + xx + 1] = v.y;
        su[y * 65 + xx + 2] = v.z; su[y * 65 + xx + 3] = v.w;
    }
    __syncthreads();
    dft_stages(su, FxR, FxI, Uxall + ((size_t)t * 256 + map) * UMAP);
}

// ---------------- upfront: all x-side mixes (v5 -- best measured: 41.4us) -------
// global -> regs (5 float4/thread, full 128B lines) -> ds_write -> barrier ->
// compute; prefetch for chunk c+1 issued before the barrier, consumed at next
// iteration's ds_write, so ~80B/lane stays in flight across the compute phase.
__global__ __launch_bounds__(256, 4) void k_mix_x(
    const float* __restrict__ Uxall,
    const float* __restrict__ sw1, const float* __restrict__ sw2,
    float* __restrict__ Sx)
{
    __shared__ float4 Wt4[2][256];    // [buf][(ii*8+oo)*4 + wl]   8 KB
    __shared__ float4 Ut4[2][1024];   // [buf][ii*256 + tb*8 + wl] 32 KB
    int blk = blockIdx.x;
    int mq = blk & 15;
    int op = (blk >> 4) & 7;
    int half = (blk >> 7) & 1;
    int li = blk >> 8;          // 0,1,2 -> layers 0,2,4
    int l = li * 2;
    int tid = threadIdx.x;
    int m0 = mq * 16;
    int o0 = op * 8;
    const float2* wsrc = (const float2*)(half ? sw2 : sw1);
    const float2* usrc = (const float2*)Uxall;

    int wl = tid & 7;                       // 16B lane-part within a 128B row
    int wrow = tid >> 3;                    // 32 rows
    int wii = wrow >> 3, woo = wrow & 7;    // W rows: 4i x 8o
    const float4* wg4 = (const float4*)(wsrc
        + (((size_t)(l * 64 + wii) * 64) + o0 + woo) * 256 + m0) + wl;
    int ut_ = wrow >> 2, ub_ = wrow & 3;    // U rows: 8t x 4b
    const float4* ug4 = (const float4*)(usrc
        + (size_t)ut_ * 131072 + (size_t)ub_ * 32768 + half * 256 + m0) + wl;

    int mt = tid & 15, pp = tid >> 4;       // compute mapping: mode, tb-pair
    float aR[8][2], aI[8][2];
    #pragma unroll
    for (int oo = 0; oo < 8; oo++) {
        aR[oo][0] = 0.f; aR[oo][1] = 0.f;
        aI[oo][0] = 0.f; aI[oo][1] = 0.f;
    }

    // prologue: chunk 0 -> regs
    float4 wv  = wg4[0];
    float4 uv0 = ug4[0];
    float4 uv1 = ug4[256];
    float4 uv2 = ug4[512];
    float4 uv3 = ug4[768];

    for (int c = 0; c < 16; ++c) {
        int cb = c & 1;
        Wt4[cb][tid] = wv;
        Ut4[cb][tid] = uv0;
        Ut4[cb][256 + tid] = uv1;
        Ut4[cb][512 + tid] = uv2;
        Ut4[cb][768 + tid] = uv3;
        if (c < 15) {
            size_t ib = (size_t)(c + 1) * 4;
            wv  = wg4[ib * 8192];
            uv0 = ug4[ib * 256];
            uv1 = ug4[(ib + 1) * 256];
            uv2 = ug4[(ib + 2) * 256];
            uv3 = ug4[(ib + 3) * 256];
        }
        __syncthreads();
        const float2* Wl = (const float2*)Wt4[cb];
        const float2* Ul = (const float2*)Ut4[cb];
        #pragma unroll
        for (int ii = 0; ii < 4; ii++) {
            float2 u0 = Ul[(ii * 32 + 2 * pp) * 16 + mt];
            float2 u1 = Ul[(ii * 32 + 2 * pp + 1) * 16 + mt];
            #pragma unroll
            for (int oo = 0; oo < 8; oo++) {
                float2 w = Wl[(ii * 8 + oo) * 16 + mt];
                aR[oo][0] = fmaf(u0.x, w.x, aR[oo][0]);
                aR[oo][0] = fmaf(-u0.y, w.y, aR[oo][0]);
                aI[oo][0] = fmaf(u0.x, w.y, aI[oo][0]);
                aI[oo][0] = fmaf(u0.y, w.x, aI[oo][0]);
                aR[oo][1] = fmaf(u1.x, w.x, aR[oo][1]);
                aR[oo][1] = fmaf(-u1.y, w.y, aR[oo][1]);
                aI[oo][1] = fmaf(u1.x, w.y, aI[oo][1]);
                aI[oo][1] = fmaf(u1.y, w.x, aI[oo][1]);
            }
        }
        __syncthreads();
    }

    float2* S2 = (float2*)Sx;
    #pragma unroll
    for (int oo = 0; oo < 8; oo++)
        #pragma unroll
        for (int j = 0; j < 2; j++) {
            int tb = 2 * pp + j;
            int t = tb >> 2, b = tb & 3;
            S2[((size_t)(li * 8 + t) * 256 + b * 64 + o0 + oo) * 512
               + half * 256 + m0 + mt] = make_float2(aR[oo][j], aI[oo][j]);
        }
}

// ---------------- 1x1-conv skip: register-tiled GEMM ----------------------------
__device__ __forceinline__ void fma16(const float4 w, const float4 u, float acc[4][4]) {
    acc[0][0] = fmaf(u.x, w.x, acc[0][0]); acc[0][1] = fmaf(u.y, w.x, acc[0][1]);
    acc[0][2] = fmaf(u.z, w.x, acc[0][2]); acc[0][3] = fmaf(u.w, w.x, acc[0][3]);
    acc[1][0] = fmaf(u.x, w.y, acc[1][0]); acc[1][1] = fmaf(u.y, w.y, acc[1][1]);
    acc[1][2] = fmaf(u.z, w.y, acc[1][2]); acc[1][3] = fmaf(u.w, w.y, acc[1][3]);
    acc[2][0] = fmaf(u.x, w.z, acc[2][0]); acc[2][1] = fmaf(u.y, w.z, acc[2][1]);
    acc[2][2] = fmaf(u.z, w.z, acc[2][2]); acc[2][3] = fmaf(u.w, w.z, acc[2][3]);
    acc[3][0] = fmaf(u.x, w.w, acc[3][0]); acc[3][1] = fmaf(u.y, w.w, acc[3][1]);
    acc[3][2] = fmaf(u.z, w.w, acc[3][2]); acc[3][3] = fmaf(u.w, w.w, acc[3][3]);
}

__device__ __forceinline__ void skip_gemm(int rr, float* __restrict__ sW,
    const float* __restrict__ uA, long long bsA,
    const float* __restrict__ uB, long long bsB,
    const float* __restrict__ skw, int lA, int lB, float gb,
    float* __restrict__ out)
{
    int pxc = rr & 31, oh = (rr >> 5) & 1, b = rr >> 6;
    int tid = threadIdx.x;
    int ot = tid & 7, pt = tid >> 3;       // 8 o-tiles x 4o, 32 px-tiles x 4px
    #pragma unroll
    for (int n = 0; n < 4; n++) {
        int idx = n * 1024 + tid * 4;
        int k = idx >> 5, oc = idx & 31;
        int p = k >> 6, i = k & 63;
        *(float4*)(sW + idx) =
            *(const float4*)(skw + (p ? lB : lA) * 4096 + i * 64 + oh * 32 + oc);
    }
    __syncthreads();
    float acc[4][4];
    #pragma unroll
    for (int oo = 0; oo < 4; oo++)
        #pragma unroll
        for (int q = 0; q < 4; q++) acc[oo][q] = 0.f;
    const float* pa = uA + (long long)b * bsA + pxc * 128 + pt * 4;
    const float* pb = uB + (long long)b * bsB + pxc * 128 + pt * 4;
    const float4* sW4 = (const float4*)sW;   // [128][8] float4
    #pragma unroll 4
    for (int i = 0; i < 64; i++) {
        float4 ua = *(const float4*)(pa + (size_t)i * HW);
        float4 wa = sW4[i * 8 + ot];
        fma16(wa, ua, acc);
        float4 ub = *(const float4*)(pb + (size_t)i * HW);
        float4 wb = sW4[(64 + i) * 8 + ot];
        fma16(wb, ub, acc);
    }
    float* op = out + ((long long)(b * 64 + oh * 32 + ot * 4)) * HW + pxc * 128 + pt * 4;
    #pragma unroll
    for (int oo = 0; oo < 4; oo++) {
        float4 r = make_float4(acc[oo][0] + gb, acc[oo][1] + gb,
                               acc[oo][2] + gb, acc[oo][3] + gb);
        *(float4*)(op + (size_t)oo * HW) = r;
    }
}

// ---------------- skip-only front kernels ---------------------------------------
__global__ __launch_bounds__(256) void k_skip_zr(
    const float* __restrict__ xt, const float* __restrict__ hb,
    const float* __restrict__ skw, const float* __restrict__ gate_b,
    float* __restrict__ zb, float* __restrict__ rhb)
{
    __shared__ float smem[4096];
    int blk = blockIdx.x;
    int g = blk >> 8;
    skip_gemm(blk & 255, smem,
              xt, (long long)TT_ * CC_ * HW, hb, (long long)CC_ * HW,
              skw, g ? 2 : 0, g ? 3 : 1, gate_b[g], g ? rhb : zb);
}

__global__ __launch_bounds__(256) void k_skip_h(
    const float* __restrict__ xt, const float* __restrict__ rhb,
    const float* __restrict__ skw, const float* __restrict__ gate_b,
    float* __restrict__ phb)
{
    __shared__ float smem[4096];
    skip_gemm(blockIdx.x, smem,
              xt, (long long)TT_ * CC_ * HW, rhb, (long long)CC_ * HW,
              skw, 4, 5, gate_b[2], phb);
}

// ---------------- inverse DFT stage 1, 512-thread variant -----------------------
__device__ __forceinline__ void idft_stage1_512(const float* __restrict__ SR,
                                                const float* __restrict__ SI,
                                                float* __restrict__ GR, float* __restrict__ GI)
{
    int tid = threadIdx.x;
    int kx = tid & 15, yb = tid >> 4;        // yb 0..31
    #pragma unroll
    for (int j = 0; j < 2; j++) {
        int y = yb + 32 * j;
        float stc, sts;
        __sincosf(STEP * (float)y, &sts, &stc);
        float ar = 0.f, ai = 0.f;
        float wr = 1.f, wi = 0.f;
        for (int k = 0; k < 16; k++) {
            float sr_ = SR[k * 16 + kx], si_ = SI[k * 16 + kx];
            ar = fmaf(sr_, wr, ar); ar = fmaf(-si_, wi, ar);
            ai = fmaf(sr_, wi, ai); ai = fmaf(si_, wr, ai);
            float t = wr * stc - wi * sts; wi = wr * sts + wi * stc; wr = t;
        }
        int q = (3 * y) & 3;
        float w2r = (q == 0) ? 1.f : ((q == 2) ? -1.f : 0.f);
        float w2i = (q == 1) ? 1.f : ((q == 3) ? -1.f : 0.f);
        for (int k = 16; k < 32; k++) {
            float sr_ = SR[k * 16 + kx], si_ = SI[k * 16 + kx];
            ar = fmaf(sr_, w2r, ar); ar = fmaf(-si_, w2i, ar);
            ai = fmaf(sr_, w2i, ai); ai = fmaf(si_, w2r, ai);
            float t = w2r * stc - w2i * sts; w2i = w2r * sts + w2i * stc; w2r = t;
        }
        GR[y * 16 + kx] = ar;
        GI[y * 16 + kx] = ai;
    }
}

// ---------------- in-kernel h-side mix: thread = one complex mode ---------------
// S[half,m] = sum_i W[l][i][o][m] * U[b*64+i][half*256+m]; 8-deep load batches.
__device__ __forceinline__ void gate_mix(int l, int b, int o, int half, int m,
    const float* __restrict__ U,
    const float* __restrict__ sw1, const float* __restrict__ sw2,
    float& sr, float& si)
{
    const float2* wp = (const float2*)(half ? sw2 : sw1)
                       + ((size_t)l * 64 * 64 + o) * 256 + m;     // i-stride 16384
    const float2* up = (const float2*)U + (size_t)b * 64 * 512 + half * 256 + m; // i-stride 512
    sr = 0.f; si = 0.f;
    for (int i = 0; i < 64; i += 8) {
        float2 w[8], u[8];
        #pragma unroll
        for (int k = 0; k < 8; k++) {
            w[k] = wp[(size_t)(i + k) * 16384];
            u[k] = up[(size_t)(i + k) * 512];
        }
        #pragma unroll
        for (int k = 0; k < 8; k++) {
            sr = fmaf(u[k].x, w[k].x, sr); sr = fmaf(-u[k].y, w[k].y, sr);
            si = fmaf(u[k].x, w[k].y, si); si = fmaf(u[k].y, w[k].x, si);
        }
    }
}

// ---------------- gate kernel zr: fused mix + idft + gates + rh DFT -------------
// grid [g(2)][map(256)] x 512 thr. Spart eliminated: mix result goes straight
// into the idft's LDS arrays.
__global__ __launch_bounds__(512) void k_gate_zr(
    const float* __restrict__ Uh, const float* __restrict__ Sx, int t,
    const float* __restrict__ sw1, const float* __restrict__ sw2,
    float* __restrict__ zb, float* __restrict__ rhb,
    const float* __restrict__ hb, float* __restrict__ Urh)
{
    __shared__ float smem[6208];
    float* SR = smem;          // 512
    float* SI = smem + 512;    // 512
    float* GR = smem + 1024;   // 1024
    float* GI = smem + 2048;   // 1024
    int g = blockIdx.x >> 8;
    int map = blockIdx.x & 255;
    int b = map >> 6, o = map & 63;
    int tid = threadIdx.x;
    int half = tid >> 8, m = tid & 255;
    {
        float sr, si;
        gate_mix(2 * g + 1, b, o, half, m, Uh, sw1, sw2, sr, si);
        float2 v = ((const float2*)Sx)[((size_t)(g * 8 + t) * 256 + map) * 512 + tid];
        SR[tid] = sr + v.x;
        SI[tid] = si + v.y;
    }
    __syncthreads();
    idft_stage1_512(SR, SI, GR, GI);
    __syncthreads();
    int x = tid & 63, ybase = tid >> 6;      // ybase 0..7
    float cx, sx;
    __sincosf(STEP * (float)x, &sx, &cx);
    size_t mo = (size_t)map * HW;
    float rhv[8];
    #pragma unroll
    for (int j = 0; j < 8; j++) {
        int y = ybase + 8 * j;
        float acc = GR[y * 16];
        float wr = cx, wi = sx;
        #pragma unroll
        for (int k = 1; k < 16; k++) {
            acc = fmaf(2.f * GR[y * 16 + k], wr, acc);
            acc = fmaf(-2.f * GI[y * 16 + k], wi, acc);
            float t2 = wr * cx - wi * sx; wi = wr * sx + wi * cx; wr = t2;
        }
        float val = acc * (1.f / 64.f);
        int idx = y * 64 + x;
        if (g == 0) {
            float pre = val + zb[mo + idx];
            zb[mo + idx] = 1.f / (1.f + __expf(-pre));
        } else {
            float pre = val + rhb[mo + idx];
            float rr = 1.f / (1.f + __expf(-pre));
            float rh = rr * hb[mo + idx];
            rhb[mo + idx] = rh;
            rhv[j] = rh;
        }
    }
    if (g == 0) return;
    __syncthreads();
    float* su = smem;
    #pragma unroll
    for (int j = 0; j < 8; j++) {
        int y = ybase + 8 * j;
        su[y * 65 + x] = rhv[j];
    }
    __syncthreads();
    dft_stages_512(su, smem + 4160, smem + 5184, Urh + (size_t)map * UMAP);
}

// ---------------- gate kernel h: fused mix + idft + GRU update + h DFT ----------
__global__ __launch_bounds__(512) void k_gate_h(
    const float* __restrict__ Urh, const float* __restrict__ Sx, int t,
    const float* __restrict__ sw1, const float* __restrict__ sw2,
    const float* __restrict__ zb, const float* __restrict__ phb,
    float* __restrict__ hb, float* __restrict__ Uh)
{
    __shared__ float smem[6208];
    float* SR = smem;
    float* SI = smem + 512;
    float* GR = smem + 1024;
    float* GI = smem + 2048;
    int map = blockIdx.x & 255;
    int b = map >> 6, o = map & 63;
    int tid = threadIdx.x;
    int half = tid >> 8, m = tid & 255;
    {
        float sr, si;
        gate_mix(5, b, o, half, m, Urh, sw1, sw2, sr, si);
        float2 v = ((const float2*)Sx)[((size_t)(2 * 8 + t) * 256 + map) * 512 + tid];
        SR[tid] = sr + v.x;
        SI[tid] = si + v.y;
    }
    __syncthreads();
    idft_stage1_512(SR, SI, GR, GI);
    __syncthreads();
    int x = tid & 63, ybase = tid >> 6;
    float cx, sx;
    __sincosf(STEP * (float)x, &sx, &cx);
    size_t mo = (size_t)map * HW;
    float hv[8];
    #pragma unroll
    for (int j = 0; j < 8; j++) {
        int y = ybase + 8 * j;
        float acc = GR[y * 16];
        float wr = cx, wi = sx;
        #pragma unroll
        for (int k = 1; k < 16; k++) {
            acc = fmaf(2.f * GR[y * 16 + k], wr, acc);
            acc = fmaf(-2.f * GI[y * 16 + k], wi, acc);
            float t2 = wr * cx - wi * sx; wi = wr * sx + wi * cx; wr = t2;
        }
        float val = acc * (1.f / 64.f);
        int idx = y * 64 + x;
        float pre = val + phb[mo + idx];
        float hh = (pre > 0.f) ? 1.0507009873554805f * pre
                               : 1.7580993408473766f * (__expf(pre) - 1.f);
        float z = zb[mo + idx];
        float hn = fmaf(z, hh - hb[mo + idx], hb[mo + idx]);
        hb[mo + idx] = hn;
        hv[j] = hn;
    }
    __syncthreads();
    float* su = smem;
    #pragma unroll
    for (int j = 0; j < 8; j++) {
        int y = ybase + 8 * j;
        su[y * 65 + x] = hv[j];
    }
    __syncthreads();
    dft_stages_512(su, smem + 4160, smem + 5184, Uh + (size_t)map * UMAP);
}

extern "C" void kernel_launch(void* const* d_in, const int* in_sizes, int n_in,
                              void* d_out, int out_size, void* d_ws, size_t ws_size,
                              hipStream_t stream)
{
    (void)in_sizes; (void)n_in; (void)out_size; (void)ws_size;
    const float* x   = (const float*)d_in[0];
    const float* sw1 = (const float*)d_in[1];
    const float* sw2 = (const float*)d_in[2];
    const float* skw = (const float*)d_in[3];
    const float* gb  = (const float*)d_in[4];
    const float* bh  = (const float*)d_in[5];
    float* ws    = (float*)d_ws;
    float* Uxall = ws + OFF_UXALL;
    float* Uh    = ws + OFF_UH;
    float* Urh   = ws + OFF_URH;
    float* Sx    = ws + OFF_SX;
    float* hb    = ws + OFF_H;
    float* zb    = ws + OFF_Z;
    float* rhb   = ws + OFF_RH;
    float* phb   = ws + OFF_PH;

    k_init<<<1280, 256, 0, stream>>>(hb, Uh, bh);
    k_dft_x<<<2048, 256, 0, stream>>>(x, Uxall);
    k_mix_x<<<768, 256, 0, stream>>>(Uxall, sw1, sw2, Sx);
    for (int t = 0; t < TT_; t++) {
        const float* xt = x + (size_t)t * CC_ * HW;
        k_skip_zr<<<512, 256, 0, stream>>>(xt, hb, skw, gb, zb, rhb);
        k_gate_zr<<<512, 512, 0, stream>>>(Uh, Sx, t, sw1, sw2, zb, rhb, hb, Urh);
        k_skip_h<<<256, 256, 0, stream>>>(xt, rhb, skw, gb, phb);
        k_gate_h<<<256, 512, 0, stream>>>(Urh, Sx, t, sw1, sw2, zb, phb, hb, Uh);
    }
    hipMemcpyAsync(d_out, hb, (size_t)BB_ * CC_ * HW * sizeof(float),
                   hipMemcpyDeviceToDevice, stream);
}

// Round 9
// 739.268 us; speedup vs baseline: 1.1554x; 1.1554x over previous
//
#include <hip/hip_runtime.h>

#define BB_ 4
#define TT_ 8
#define CC_ 64
#define HW 4096
#define UMAP 1024      // floats per (b,c) spectrum map: 32 ky * 16 kx * 2
#define STEP 0.09817477042468103f   // 2*pi/64

// ws float offsets (SPART region now holds 6 slots; layout unchanged)
#define OFF_UXALL 0                                     // 8*256*1024
#define OFF_UH    (OFF_UXALL + TT_*256*UMAP)            // 256*1024
#define OFF_URH   (OFF_UH + 256*UMAP)                   // 256*1024
#define OFF_SX    (OFF_URH + 256*UMAP)                  // 3 slots * 8 t * 256 maps * 1024
#define OFF_SPART (OFF_SX + 3*TT_*256*UMAP)
#define OFF_H     (OFF_SPART + 2*8*256*UMAP)
#define OFF_Z     (OFF_H + BB_*CC_*HW)
#define OFF_RH    (OFF_Z + BB_*CC_*HW)
#define OFF_PH    (OFF_RH + BB_*CC_*HW)

// ---------------- init: h = bias, Uh = spectrum of constant map ----------------
__global__ __launch_bounds__(256) void k_init(float* __restrict__ hb,
                                              float* __restrict__ Uh,
                                              const float* __restrict__ bias_h) {
    float v = bias_h[0];
    int blk = blockIdx.x;
    if (blk < 1024) {
        int idx = (blk * 256 + threadIdx.x) * 4;
        *(float4*)(hb + idx) = make_float4(v, v, v, v);
    } else {
        // spectrum of constant v map: only (ky=0,kx=0) = 4096*v/64 = 64*v
        int map = blk - 1024;
        float4 z = make_float4(0.f, 0.f, 0.f, 0.f);
        if (threadIdx.x == 0) z.x = 64.f * v;
        *(float4*)(Uh + (size_t)map * UMAP + threadIdx.x * 4) = z;
    }
}

// ---------------- forward partial DFT stages, 256-thread variant ----------------
__device__ __forceinline__ void dft_stages(const float* __restrict__ su,
                                           float* __restrict__ FxR, float* __restrict__ FxI,
                                           float* __restrict__ dst) {
    int tid = threadIdx.x;
    int kx = tid & 15, yb = tid >> 4;
    float stc, sts;
    __sincosf(-STEP * (float)kx, &sts, &stc);
    float wr = 1.f, wi = 0.f;
    float aR[4] = {0, 0, 0, 0}, aI[4] = {0, 0, 0, 0};
    for (int x = 0; x < 64; x++) {
        #pragma unroll
        for (int j = 0; j < 4; j++) {
            float v = su[(yb + 16 * j) * 65 + x];
            aR[j] = fmaf(v, wr, aR[j]);
            aI[j] = fmaf(v, wi, aI[j]);
        }
        float t = wr * stc - wi * sts;
        wi = wr * sts + wi * stc;
        wr = t;
    }
    #pragma unroll
    for (int j = 0; j < 4; j++) {
        FxR[(yb + 16 * j) * 16 + kx] = aR[j];
        FxI[(yb + 16 * j) * 16 + kx] = aI[j];
    }
    __syncthreads();
    int kb = tid >> 4;
    float c0, s0, c1, s1;
    __sincosf(-STEP * (float)kb, &s0, &c0);
    __sincosf(-STEP * (float)(kb + 48), &s1, &c1);
    float w0r = 1, w0i = 0, w1r = 1, w1i = 0;
    float A0r = 0, A0i = 0, A1r = 0, A1i = 0;
    for (int y = 0; y < 64; y++) {
        float Fr = FxR[y * 16 + kx], Fi = FxI[y * 16 + kx];
        A0r = fmaf(Fr, w0r, A0r); A0r = fmaf(-Fi, w0i, A0r);
        A0i = fmaf(Fr, w0i, A0i); A0i = fmaf(Fi, w0r, A0i);
        A1r = fmaf(Fr, w1r, A1r); A1r = fmaf(-Fi, w1i, A1r);
        A1i = fmaf(Fr, w1i, A1i); A1i = fmaf(Fi, w1r, A1i);
        float t0 = w0r * c0 - w0i * s0; w0i = w0r * s0 + w0i * c0; w0r = t0;
        float t1 = w1r * c1 - w1i * s1; w1i = w1r * s1 + w1i * c1; w1r = t1;
    }
    const float sc = 1.f / 64.f;
    float2* d2 = (float2*)dst;
    d2[kb * 16 + kx]        = make_float2(A0r * sc, A0i * sc);
    d2[(kb + 16) * 16 + kx] = make_float2(A1r * sc, A1i * sc);
}

// ---------------- forward DFT stages, 512-thread variant ------------------------
__device__ __forceinline__ void dft_stages_512(const float* __restrict__ su,
                                               float* __restrict__ FxR, float* __restrict__ FxI,
                                               float* __restrict__ dst) {
    int tid = threadIdx.x;
    int kx = tid & 15, yb = tid >> 4;            // yb 0..31
    float stc, sts;
    __sincosf(-STEP * (float)kx, &sts, &stc);
    float wr = 1.f, wi = 0.f;
    float aR[2] = {0, 0}, aI[2] = {0, 0};
    for (int x = 0; x < 64; x++) {
        #pragma unroll
        for (int j = 0; j < 2; j++) {
            float v = su[(yb + 32 * j) * 65 + x];
            aR[j] = fmaf(v, wr, aR[j]);
            aI[j] = fmaf(v, wi, aI[j]);
        }
        float t = wr * stc - wi * sts;
        wi = wr * sts + wi * stc;
        wr = t;
    }
    #pragma unroll
    for (int j = 0; j < 2; j++) {
        FxR[(yb + 32 * j) * 16 + kx] = aR[j];
        FxI[(yb + 32 * j) * 16 + kx] = aI[j];
    }
    __syncthreads();
    int kb = tid >> 4;                           // 0..31 = output row
    int ky = (kb < 16) ? kb : kb + 32;           // rows 16..31 hold ky 48..63
    float c0, s0;
    __sincosf(-STEP * (float)ky, &s0, &c0);
    float w0r = 1, w0i = 0, A0r = 0, A0i = 0;
    for (int y = 0; y < 64; y++) {
        float Fr = FxR[y * 16 + kx], Fi = FxI[y * 16 + kx];
        A0r = fmaf(Fr, w0r, A0r); A0r = fmaf(-Fi, w0i, A0r);
        A0i = fmaf(Fr, w0i, A0i); A0i = fmaf(Fi, w0r, A0i);
        float t0 = w0r * c0 - w0i * s0; w0i = w0r * s0 + w0i * c0; w0r = t0;
    }
    const float sc = 1.f / 64.f;
    ((float2*)dst)[kb * 16 + kx] = make_float2(A0r * sc, A0i * sc);
}

// ---------------- batched DFT of all x_t maps (once per launch) ----------------
__global__ __launch_bounds__(256) void k_dft_x(const float* __restrict__ x,
                                               float* __restrict__ Uxall) {
    __shared__ float su[64 * 65];
    __shared__ float FxR[1024], FxI[1024];
    int blk = blockIdx.x;
    int t = blk >> 8, map = blk & 255;
    int b = map >> 6, c = map & 63;
    const float* src = x + (((size_t)b * TT_ + t) * CC_ + c) * HW;
    int tid = threadIdx.x;
    #pragma unroll
    for (int k = 0; k < 4; k++) {
        int off = k * 1024 + tid * 4;
        float4 v = *(const float4*)(src + off);
        int y = off >> 6, xx = off & 63;
        su[y * 65 + xx + 0] = v.x; su[y * 65 + xx + 1] = v.y;
        su[y * 65 + xx + 2] = v.z; su[y * 65 + xx + 3] = v.w;
    }
    __syncthreads();
    dft_stages(su, FxR, FxI, Uxall + ((size_t)t * 256 + map) * UMAP);
}

// ---------------- mix accumulation core -----------------------------------------
__device__ __forceinline__ void mix_load(const float2* __restrict__ W2,
                                         const float2* __restrict__ U2, int i,
                                         float2 w[4], float2 u[4]) {
    const float2* wp = W2 + (size_t)i * 16384;
    const float2* up = U2 + (size_t)i * 512;
    w[0] = wp[0]; w[1] = wp[256]; w[2] = wp[512]; w[3] = wp[768];
    u[0] = up[0]; u[1] = up[32768]; u[2] = up[65536]; u[3] = up[98304];
}

__device__ __forceinline__ void mix_fma(const float2 w[4], const float2 u[4],
                                        float aR[4][4], float aI[4][4]) {
    #pragma unroll
    for (int oo = 0; oo < 4; oo++)
        #pragma unroll
        for (int bb = 0; bb < 4; bb++) {
            aR[oo][bb] = fmaf(u[bb].x, w[oo].x, aR[oo][bb]);
            aR[oo][bb] = fmaf(-u[bb].y, w[oo].y, aR[oo][bb]);
            aI[oo][bb] = fmaf(u[bb].x, w[oo].y, aI[oo][bb]);
            aI[oo][bb] = fmaf(u[bb].y, w[oo].x, aI[oo][bb]);
        }
}

// depth-3 pipeline (h-side mixes; niter=32 now -> prologue overhead 6% not 25%)
__device__ __forceinline__ void mix_accum(const float2* __restrict__ W2,
                                          const float2* __restrict__ U2,
                                          int niter, float aR[4][4], float aI[4][4])
{
    float2 wA[4], uA[4], wB[4], uB[4], wN[4], uN[4];
    mix_load(W2, U2, 0, wA, uA);
    mix_load(W2, U2, 1, wB, uB);
    for (int i = 0; i + 2 < niter; i += 2) {
        mix_load(W2, U2, i + 2, wN, uN);
        mix_fma(wA, uA, aR, aI);
        #pragma unroll
        for (int k = 0; k < 4; k++) { wA[k] = wN[k]; uA[k] = uN[k]; }
        mix_load(W2, U2, i + 3, wN, uN);
        mix_fma(wB, uB, aR, aI);
        #pragma unroll
        for (int k = 0; k < 4; k++) { wB[k] = wN[k]; uB[k] = uN[k]; }
    }
    mix_fma(wA, uA, aR, aI);
    mix_fma(wB, uB, aR, aI);
}

// ---------------- upfront: all x-side mixes (v5 -- best measured: 41.4us) -------
// global -> regs (5 float4/thread, full 128B lines) -> ds_write -> barrier ->
// compute; prefetch for chunk c+1 issued before the barrier, consumed at next
// iteration's ds_write, so ~80B/lane stays in flight across the compute phase.
__global__ __launch_bounds__(256, 4) void k_mix_x(
    const float* __restrict__ Uxall,
    const float* __restrict__ sw1, const float* __restrict__ sw2,
    float* __restrict__ Sx)
{
    __shared__ float4 Wt4[2][256];    // [buf][(ii*8+oo)*4 + wl]   8 KB
    __shared__ float4 Ut4[2][1024];   // [buf][ii*256 + tb*8 + wl] 32 KB
    int blk = blockIdx.x;
    int mq = blk & 15;
    int op = (blk >> 4) & 7;
    int half = (blk >> 7) & 1;
    int li = blk >> 8;          // 0,1,2 -> layers 0,2,4
    int l = li * 2;
    int tid = threadIdx.x;
    int m0 = mq * 16;
    int o0 = op * 8;
    const float2* wsrc = (const float2*)(half ? sw2 : sw1);
    const float2* usrc = (const float2*)Uxall;

    int wl = tid & 7;                       // 16B lane-part within a 128B row
    int wrow = tid >> 3;                    // 32 rows
    int wii = wrow >> 3, woo = wrow & 7;    // W rows: 4i x 8o
    const float4* wg4 = (const float4*)(wsrc
        + (((size_t)(l * 64 + wii) * 64) + o0 + woo) * 256 + m0) + wl;
    int ut_ = wrow >> 2, ub_ = wrow & 3;    // U rows: 8t x 4b
    const float4* ug4 = (const float4*)(usrc
        + (size_t)ut_ * 131072 + (size_t)ub_ * 32768 + half * 256 + m0) + wl;

    int mt = tid & 15, pp = tid >> 4;       // compute mapping: mode, tb-pair
    float aR[8][2], aI[8][2];
    #pragma unroll
    for (int oo = 0; oo < 8; oo++) {
        aR[oo][0] = 0.f; aR[oo][1] = 0.f;
        aI[oo][0] = 0.f; aI[oo][1] = 0.f;
    }

    // prologue: chunk 0 -> regs
    float4 wv  = wg4[0];
    float4 uv0 = ug4[0];
    float4 uv1 = ug4[256];
    float4 uv2 = ug4[512];
    float4 uv3 = ug4[768];

    for (int c = 0; c < 16; ++c) {
        int cb = c & 1;
        Wt4[cb][tid] = wv;
        Ut4[cb][tid] = uv0;
        Ut4[cb][256 + tid] = uv1;
        Ut4[cb][512 + tid] = uv2;
        Ut4[cb][768 + tid] = uv3;
        if (c < 15) {
            size_t ib = (size_t)(c + 1) * 4;
            wv  = wg4[ib * 8192];
            uv0 = ug4[ib * 256];
            uv1 = ug4[(ib + 1) * 256];
            uv2 = ug4[(ib + 2) * 256];
            uv3 = ug4[(ib + 3) * 256];
        }
        __syncthreads();
        const float2* Wl = (const float2*)Wt4[cb];
        const float2* Ul = (const float2*)Ut4[cb];
        #pragma unroll
        for (int ii = 0; ii < 4; ii++) {
            float2 u0 = Ul[(ii * 32 + 2 * pp) * 16 + mt];
            float2 u1 = Ul[(ii * 32 + 2 * pp + 1) * 16 + mt];
            #pragma unroll
            for (int oo = 0; oo < 8; oo++) {
                float2 w = Wl[(ii * 8 + oo) * 16 + mt];
                aR[oo][0] = fmaf(u0.x, w.x, aR[oo][0]);
                aR[oo][0] = fmaf(-u0.y, w.y, aR[oo][0]);
                aI[oo][0] = fmaf(u0.x, w.y, aI[oo][0]);
                aI[oo][0] = fmaf(u0.y, w.x, aI[oo][0]);
                aR[oo][1] = fmaf(u1.x, w.x, aR[oo][1]);
                aR[oo][1] = fmaf(-u1.y, w.y, aR[oo][1]);
                aI[oo][1] = fmaf(u1.x, w.y, aI[oo][1]);
                aI[oo][1] = fmaf(u1.y, w.x, aI[oo][1]);
            }
        }
        __syncthreads();
    }

    float2* S2 = (float2*)Sx;
    #pragma unroll
    for (int oo = 0; oo < 8; oo++)
        #pragma unroll
        for (int j = 0; j < 2; j++) {
            int tb = 2 * pp + j;
            int t = tb >> 2, b = tb & 3;
            S2[((size_t)(li * 8 + t) * 256 + b * 64 + o0 + oo) * 512
               + half * 256 + m0 + mt] = make_float2(aR[oo][j], aI[oo][j]);
        }
}

// ---------------- per-step h-side mix body, 2-way i-shard -----------------------
// r bits: [half(1)][ic(1)][og(16)] = 64 blocks per layer. 32 i per block.
// Spart slots: z -> 0,1; r -> 2,3; h -> 4,5. Slot = slotbase + ic.
__device__ __forceinline__ void mix_body2(int r, int l, int slotbase,
    const float* __restrict__ U,
    const float* __restrict__ sw1, const float* __restrict__ sw2,
    float* __restrict__ Spart)
{
    int og = r & 15;
    int ic = (r >> 4) & 1;
    int half = r >> 5;
    int m = threadIdx.x;
    int o0 = og * 4, ib = ic * 32;
    const float2* wt = (const float2*)(half ? sw2 : sw1);
    const float2* W2 = wt + (((size_t)l * 64 + ib) * 64 + o0) * 256 + m;
    const float2* U2 = (const float2*)U + (size_t)ib * 512 + half * 256 + m;
    float aR[4][4], aI[4][4];
    #pragma unroll
    for (int oo = 0; oo < 4; oo++)
        #pragma unroll
        for (int b = 0; b < 4; b++) { aR[oo][b] = 0.f; aI[oo][b] = 0.f; }
    mix_accum(W2, U2, 32, aR, aI);
    int slot = slotbase + ic;
    float2* S2 = (float2*)Spart;
    #pragma unroll
    for (int oo = 0; oo < 4; oo++)
        #pragma unroll
        for (int b = 0; b < 4; b++)
            S2[((size_t)slot * 256 + b * 64 + o0 + oo) * 512 + half * 256 + m]
                = make_float2(aR[oo][b], aI[oo][b]);
}

// ---------------- 1x1-conv skip: register-tiled GEMM ----------------------------
__device__ __forceinline__ void fma16(const float4 w, const float4 u, float acc[4][4]) {
    acc[0][0] = fmaf(u.x, w.x, acc[0][0]); acc[0][1] = fmaf(u.y, w.x, acc[0][1]);
    acc[0][2] = fmaf(u.z, w.x, acc[0][2]); acc[0][3] = fmaf(u.w, w.x, acc[0][3]);
    acc[1][0] = fmaf(u.x, w.y, acc[1][0]); acc[1][1] = fmaf(u.y, w.y, acc[1][1]);
    acc[1][2] = fmaf(u.z, w.y, acc[1][2]); acc[1][3] = fmaf(u.w, w.y, acc[1][3]);
    acc[2][0] = fmaf(u.x, w.z, acc[2][0]); acc[2][1] = fmaf(u.y, w.z, acc[2][1]);
    acc[2][2] = fmaf(u.z, w.z, acc[2][2]); acc[2][3] = fmaf(u.w, w.z, acc[2][3]);
    acc[3][0] = fmaf(u.x, w.w, acc[3][0]); acc[3][1] = fmaf(u.y, w.w, acc[3][1]);
    acc[3][2] = fmaf(u.z, w.w, acc[3][2]); acc[3][3] = fmaf(u.w, w.w, acc[3][3]);
}

__device__ __forceinline__ void skip_gemm(int rr, float* __restrict__ sW,
    const float* __restrict__ uA, long long bsA,
    const float* __restrict__ uB, long long bsB,
    const float* __restrict__ skw, int lA, int lB, float gb,
    float* __restrict__ out)
{
    int pxc = rr & 31, oh = (rr >> 5) & 1, b = rr >> 6;
    int tid = threadIdx.x;
    int ot = tid & 7, pt = tid >> 3;       // 8 o-tiles x 4o, 32 px-tiles x 4px
    #pragma unroll
    for (int n = 0; n < 4; n++) {
        int idx = n * 1024 + tid * 4;
        int k = idx >> 5, oc = idx & 31;
        int p = k >> 6, i = k & 63;
        *(float4*)(sW + idx) =
            *(const float4*)(skw + (p ? lB : lA) * 4096 + i * 64 + oh * 32 + oc);
    }
    __syncthreads();
    float acc[4][4];
    #pragma unroll
    for (int oo = 0; oo < 4; oo++)
        #pragma unroll
        for (int q = 0; q < 4; q++) acc[oo][q] = 0.f;
    const float* pa = uA + (long long)b * bsA + pxc * 128 + pt * 4;
    const float* pb = uB + (long long)b * bsB + pxc * 128 + pt * 4;
    const float4* sW4 = (const float4*)sW;   // [128][8] float4
    #pragma unroll 4
    for (int i = 0; i < 64; i++) {
        float4 ua = *(const float4*)(pa + (size_t)i * HW);
        float4 wa = sW4[i * 8 + ot];
        fma16(wa, ua, acc);
        float4 ub = *(const float4*)(pb + (size_t)i * HW);
        float4 wb = sW4[(64 + i) * 8 + ot];
        fma16(wb, ub, acc);
    }
    float* op = out + ((long long)(b * 64 + oh * 32 + ot * 4)) * HW + pxc * 128 + pt * 4;
    #pragma unroll
    for (int oo = 0; oo < 4; oo++) {
        float4 r = make_float4(acc[oo][0] + gb, acc[oo][1] + gb,
                               acc[oo][2] + gb, acc[oo][3] + gb);
        *(float4*)(op + (size_t)oo * HW) = r;
    }
}

// ---------------- inverse DFT stage 1, 256-thread variant -----------------------
__device__ __forceinline__ void idft_stage1_256(const float* __restrict__ SR,
                                                const float* __restrict__ SI,
                                                float* __restrict__ GR, float* __restrict__ GI)
{
    int tid = threadIdx.x;
    int kx = tid & 15, yb = tid >> 4;
    #pragma unroll
    for (int j = 0; j < 4; j++) {
        int y = yb + 16 * j;
        float stc, sts;
        __sincosf(STEP * (float)y, &sts, &stc);
        float ar = 0.f, ai = 0.f;
        float wr = 1.f, wi = 0.f;
        for (int k = 0; k < 16; k++) {
            float sr_ = SR[k * 16 + kx], si_ = SI[k * 16 + kx];
            ar = fmaf(sr_, wr, ar); ar = fmaf(-si_, wi, ar);
            ai = fmaf(sr_, wi, ai); ai = fmaf(si_, wr, ai);
            float t = wr * stc - wi * sts; wi = wr * sts + wi * stc; wr = t;
        }
        int q = (3 * y) & 3;
        float w2r = (q == 0) ? 1.f : ((q == 2) ? -1.f : 0.f);
        float w2i = (q == 1) ? 1.f : ((q == 3) ? -1.f : 0.f);
        for (int k = 16; k < 32; k++) {
            float sr_ = SR[k * 16 + kx], si_ = SI[k * 16 + kx];
            ar = fmaf(sr_, w2r, ar); ar = fmaf(-si_, w2i, ar);
            ai = fmaf(sr_, w2i, ai); ai = fmaf(si_, w2r, ai);
            float t = w2r * stc - w2i * sts; w2i = w2r * sts + w2i * stc; w2r = t;
        }
        GR[y * 16 + kx] = ar;
        GI[y * 16 + kx] = ai;
    }
}

// ---------------- z-gate finalize (256 thr) -------------------------------------
// Reads Spart slots 0,1 (this step's front_zr; race-free: front_h's mix writes
// slots 4,5) + Sx slot t; idft + sigmoid into zb.
__device__ __forceinline__ void z_finalize(int map, int t,
    const float* __restrict__ Spart, const float* __restrict__ Sx,
    float* __restrict__ zb, float* __restrict__ smem)
{
    float* SR = smem;          // 512
    float* SI = smem + 512;    // 512
    float* GR = smem + 1024;   // 1024
    float* GI = smem + 2048;   // 1024
    int tid = threadIdx.x;
    {
        float4 v = ((const float4*)Sx)[((size_t)t * 256 + map) * 256 + tid];
        float sxr = v.x, sxi = v.y, syr = v.z, syi = v.w;
        const float4* base = (const float4*)Spart;
        #pragma unroll
        for (int ic = 0; ic < 2; ic++) {
            float4 p = base[((size_t)ic * 256 + map) * 256 + tid];
            sxr += p.x; sxi += p.y; syr += p.z; syi += p.w;
        }
        SR[2 * tid] = sxr; SI[2 * tid] = sxi;
        SR[2 * tid + 1] = syr; SI[2 * tid + 1] = syi;
    }
    __syncthreads();
    idft_stage1_256(SR, SI, GR, GI);
    __syncthreads();
    int x = tid & 63, ybase = tid >> 6;
    float cx, sx;
    __sincosf(STEP * (float)x, &sx, &cx);
    size_t mo = (size_t)map * HW;
    #pragma unroll
    for (int j = 0; j < 16; j++) {
        int y = ybase + 4 * j;
        float acc = GR[y * 16];
        float wr = cx, wi = sx;
        #pragma unroll
        for (int k = 1; k < 16; k++) {
            acc = fmaf(2.f * GR[y * 16 + k], wr, acc);
            acc = fmaf(-2.f * GI[y * 16 + k], wi, acc);
            float t2 = wr * cx - wi * sx; wi = wr * sx + wi * cx; wr = t2;
        }
        float val = acc * (1.f / 64.f);
        int idx = y * 64 + x;
        float pre = val + zb[mo + idx];
        zb[mo + idx] = 1.f / (1.f + __expf(-pre));
    }
}

// ---------------- fused front kernels -------------------------------------------
// front_zr: 640 blocks = 128 mix (z: slots 0,1 / r: slots 2,3; first so the
// 32-iter blocks start at t=0) + 512 skip.
__global__ __launch_bounds__(256) void k_front_zr(
    const float* __restrict__ Uh,
    const float* __restrict__ xt, const float* __restrict__ hb,
    const float* __restrict__ sw1, const float* __restrict__ sw2,
    const float* __restrict__ skw, const float* __restrict__ gate_b,
    float* __restrict__ Spart, float* __restrict__ zb, float* __restrict__ rhb)
{
    __shared__ float smem[4096];
    int blk = blockIdx.x;
    if (blk < 128) {
        int g = blk >> 6;
        mix_body2(blk & 63, g ? 3 : 1, g * 2, Uh, sw1, sw2, Spart);
    } else {
        int r = blk - 128;
        int g = r >> 8;
        skip_gemm(r & 255, smem,
                  xt, (long long)TT_ * CC_ * HW, hb, (long long)CC_ * HW,
                  skw, g ? 2 : 0, g ? 3 : 1, gate_b[g], g ? rhb : zb);
    }
}

// front_h: 576 blocks = 64 mix (l=5, slots 4,5) + 256 z-finalize + 256 skip.
__global__ __launch_bounds__(256) void k_front_h(
    const float* __restrict__ Urh,
    const float* __restrict__ xt, const float* __restrict__ rhb,
    const float* __restrict__ sw1, const float* __restrict__ sw2,
    const float* __restrict__ skw, const float* __restrict__ gate_b,
    float* __restrict__ Spart, float* __restrict__ phb,
    const float* __restrict__ Sx, int t, float* __restrict__ zb)
{
    __shared__ float smem[4096];
    int blk = blockIdx.x;
    if (blk < 64) {
        mix_body2(blk, 5, 4, Urh, sw1, sw2, Spart);
    } else if (blk < 320) {
        z_finalize(blk - 64, t, Spart, Sx, zb, smem);
    } else {
        int r = blk - 320;
        skip_gemm(r, smem,
                  xt, (long long)TT_ * CC_ * HW, rhb, (long long)CC_ * HW,
                  skw, 4, 5, gate_b[2], phb);
    }
}

// ---------------- inverse DFT stage 1, 512-thread variant -----------------------
__device__ __forceinline__ void idft_stage1_512(const float* __restrict__ SR,
                                                const float* __restrict__ SI,
                                                float* __restrict__ GR, float* __restrict__ GI)
{
    int tid = threadIdx.x;
    int kx = tid & 15, yb = tid >> 4;        // yb 0..31
    #pragma unroll
    for (int j = 0; j < 2; j++) {
        int y = yb + 32 * j;
        float stc, sts;
        __sincosf(STEP * (float)y, &sts, &stc);
        float ar = 0.f, ai = 0.f;
        float wr = 1.f, wi = 0.f;
        for (int k = 0; k < 16; k++) {
            float sr_ = SR[k * 16 + kx], si_ = SI[k * 16 + kx];
            ar = fmaf(sr_, wr, ar); ar = fmaf(-si_, wi, ar);
            ai = fmaf(sr_, wi, ai); ai = fmaf(si_, wr, ai);
            float t = wr * stc - wi * sts; wi = wr * sts + wi * stc; wr = t;
        }
        int q = (3 * y) & 3;
        float w2r = (q == 0) ? 1.f : ((q == 2) ? -1.f : 0.f);
        float w2i = (q == 1) ? 1.f : ((q == 3) ? -1.f : 0.f);
        for (int k = 16; k < 32; k++) {
            float sr_ = SR[k * 16 + kx], si_ = SI[k * 16 + kx];
            ar = fmaf(sr_, w2r, ar); ar = fmaf(-si_, w2i, ar);
            ai = fmaf(sr_, w2i, ai); ai = fmaf(si_, w2r, ai);
            float t = w2r * stc - w2i * sts; w2i = w2r * sts + w2i * stc; w2r = t;
        }
        GR[y * 16 + kx] = ar;
        GI[y * 16 + kx] = ai;
    }
}

// ---------------- back kernel zr (512 thr): r-gate + rh DFT ---------------------
__global__ __launch_bounds__(512) void k_back_zr(
    const float* __restrict__ Spart, const float* __restrict__ Sx, int t,
    float* __restrict__ rhb,
    const float* __restrict__ hb, float* __restrict__ Urh)
{
    __shared__ float smem[6208];
    float* SR = smem;          // 512
    float* SI = smem + 512;    // 512
    float* GR = smem + 1024;   // 1024
    float* GI = smem + 2048;   // 1024
    int map = blockIdx.x;
    int tid = threadIdx.x;
    {
        float2 v = ((const float2*)Sx)[((size_t)(8 + t) * 256 + map) * 512 + tid];
        float sr = v.x, si = v.y;
        const float2* base = (const float2*)Spart;
        #pragma unroll
        for (int s = 2; s < 4; s++) {
            float2 p = base[((size_t)s * 256 + map) * 512 + tid];
            sr += p.x; si += p.y;
        }
        SR[tid] = sr; SI[tid] = si;
    }
    __syncthreads();
    idft_stage1_512(SR, SI, GR, GI);
    __syncthreads();
    int x = tid & 63, ybase = tid >> 6;      // ybase 0..7
    float cx, sx;
    __sincosf(STEP * (float)x, &sx, &cx);
    size_t mo = (size_t)map * HW;
    float rhv[8];
    #pragma unroll
    for (int j = 0; j < 8; j++) {
        int y = ybase + 8 * j;
        float acc = GR[y * 16];
        float wr = cx, wi = sx;
        #pragma unroll
        for (int k = 1; k < 16; k++) {
            acc = fmaf(2.f * GR[y * 16 + k], wr, acc);
            acc = fmaf(-2.f * GI[y * 16 + k], wi, acc);
            float t2 = wr * cx - wi * sx; wi = wr * sx + wi * cx; wr = t2;
        }
        float val = acc * (1.f / 64.f);
        int idx = y * 64 + x;
        float pre = val + rhb[mo + idx];
        float rr = 1.f / (1.f + __expf(-pre));
        float rh = rr * hb[mo + idx];
        rhb[mo + idx] = rh;
        rhv[j] = rh;
    }
    __syncthreads();
    float* su = smem;
    #pragma unroll
    for (int j = 0; j < 8; j++) {
        int y = ybase + 8 * j;
        su[y * 65 + x] = rhv[j];
    }
    __syncthreads();
    dft_stages_512(su, smem + 4160, smem + 5184, Urh + (size_t)map * UMAP);
}

// ---------------- back kernel h (512 thr): idft + GRU update + fused h DFT ------
__global__ __launch_bounds__(512) void k_back_h(
    const float* __restrict__ Spart, const float* __restrict__ Sx, int t,
    const float* __restrict__ zb, const float* __restrict__ phb,
    float* __restrict__ hb, float* __restrict__ Uh)
{
    __shared__ float smem[6208];
    float* SR = smem;
    float* SI = smem + 512;
    float* GR = smem + 1024;
    float* GI = smem + 2048;
    int map = blockIdx.x & 255;
    int tid = threadIdx.x;
    {
        float2 v = ((const float2*)Sx)[((size_t)(2 * 8 + t) * 256 + map) * 512 + tid];
        float sr = v.x, si = v.y;
        const float2* base = (const float2*)Spart;
        #pragma unroll
        for (int s = 4; s < 6; s++) {
            float2 p = base[((size_t)s * 256 + map) * 512 + tid];
            sr += p.x; si += p.y;
        }
        SR[tid] = sr; SI[tid] = si;
    }
    __syncthreads();
    idft_stage1_512(SR, SI, GR, GI);
    __syncthreads();
    int x = tid & 63, ybase = tid >> 6;
    float cx, sx;
    __sincosf(STEP * (float)x, &sx, &cx);
    size_t mo = (size_t)map * HW;
    float hv[8];
    #pragma unroll
    for (int j = 0; j < 8; j++) {
        int y = ybase + 8 * j;
        float acc = GR[y * 16];
        float wr = cx, wi = sx;
        #pragma unroll
        for (int k = 1; k < 16; k++) {
            acc = fmaf(2.f * GR[y * 16 + k], wr, acc);
            acc = fmaf(-2.f * GI[y * 16 + k], wi, acc);
            float t2 = wr * cx - wi * sx; wi = wr * sx + wi * cx; wr = t2;
        }
        float val = acc * (1.f / 64.f);
        int idx = y * 64 + x;
        float pre = val + phb[mo + idx];
        float hh = (pre > 0.f) ? 1.0507009873554805f * pre
                               : 1.7580993408473766f * (__expf(pre) - 1.f);
        float z = zb[mo + idx];
        float hn = fmaf(z, hh - hb[mo + idx], hb[mo + idx]);
        hb[mo + idx] = hn;
        hv[j] = hn;
    }
    __syncthreads();
    float* su = smem;
    #pragma unroll
    for (int j = 0; j < 8; j++) {
        int y = ybase + 8 * j;
        su[y * 65 + x] = hv[j];
    }
    __syncthreads();
    dft_stages_512(su, smem + 4160, smem + 5184, Uh + (size_t)map * UMAP);
}

extern "C" void kernel_launch(void* const* d_in, const int* in_sizes, int n_in,
                              void* d_out, int out_size, void* d_ws, size_t ws_size,
                              hipStream_t stream)
{
    (void)in_sizes; (void)n_in; (void)out_size; (void)ws_size;
    const float* x   = (const float*)d_in[0];
    const float* sw1 = (const float*)d_in[1];
    const float* sw2 = (const float*)d_in[2];
    const float* skw = (const float*)d_in[3];
    const float* gb  = (const float*)d_in[4];
    const float* bh  = (const float*)d_in[5];
    float* ws    = (float*)d_ws;
    float* Uxall = ws + OFF_UXALL;
    float* Uh    = ws + OFF_UH;
    float* Urh   = ws + OFF_URH;
    float* Sx    = ws + OFF_SX;
    float* Sp    = ws + OFF_SPART;
    float* hb    = ws + OFF_H;
    float* zb    = ws + OFF_Z;
    float* rhb   = ws + OFF_RH;
    float* phb   = ws + OFF_PH;

    k_init<<<1280, 256, 0, stream>>>(hb, Uh, bh);
    k_dft_x<<<2048, 256, 0, stream>>>(x, Uxall);
    k_mix_x<<<768, 256, 0, stream>>>(Uxall, sw1, sw2, Sx);
    for (int t = 0; t < TT_; t++) {
        const float* xt = x + (size_t)t * CC_ * HW;
        k_front_zr<<<640, 256, 0, stream>>>(Uh, xt, hb, sw1, sw2, skw, gb,
                                            Sp, zb, rhb);
        k_back_zr<<<256, 512, 0, stream>>>(Sp, Sx, t, rhb, hb, Urh);
        k_front_h<<<576, 256, 0, stream>>>(Urh, xt, rhb, sw1, sw2, skw, gb,
                                           Sp, phb, Sx, t, zb);
        k_back_h<<<256, 512, 0, stream>>>(Sp, Sx, t, zb, phb, hb, Uh);
    }
    hipMemcpyAsync(d_out, hb, (size_t)BB_ * CC_ * HW * sizeof(float),
                   hipMemcpyDeviceToDevice, stream);
}